// Round 8
// baseline (433.024 us; speedup 1.0000x reference)
//
#include <hip/hip_runtime.h>
#include <math.h>

#define N_NODES 100000
#define N_EDGES 1200000
#define DIM 64
#define ELL_SLOTS 40      // max (deg+1); Poisson(12) => P(deg>=40) ~ 1e-10
#define GEMM_BLOCKS ((N_NODES + 63) / 64)    // 1563 (64 nodes/block)
#define FILL_BLOCKS ((N_EDGES + 255) / 256)  // 4688

struct Edge { int s; float nrm; };   // 8B

// ---------------- gemm tile: 64 nodes/block, LDS-staged x, W in VGPRs -------

__device__ __forceinline__ void gemm_block(int bid, const float* __restrict__ x,
                                           const float* __restrict__ W,
                                           float* __restrict__ h) {
    __shared__ float4 Xlds[1024];           // 64 rows x 16 float4 = 16 KB
    const int tid = threadIdx.x;
    const int lane = tid & 63;

    float wreg[64];                         // W column for this lane (L2-hot)
#pragma unroll
    for (int k = 0; k < 64; ++k) wreg[k] = W[k * DIM + lane];

    const int base = bid * 64;
#pragma unroll
    for (int it = 0; it < 4; ++it) {
        int f = tid + it * 256;             // float4 index in tile
        int row = base + (f >> 4);
        if (row >= N_NODES) row = N_NODES - 1;          // clamp (value unused)
        Xlds[f] = ((const float4*)x)[row * 16 + (f & 15)];
    }
    __syncthreads();

    const int m0 = (tid >> 6) * 16;         // wave's 16 rows
    for (int m = 0; m < 16; ++m) {
        const float4* xr = &Xlds[(m0 + m) * 16];
        float a0 = 0.f, a1 = 0.f, a2 = 0.f, a3 = 0.f;
#pragma unroll
        for (int k4 = 0; k4 < 16; ++k4) {
            float4 xv = xr[k4];             // uniform b128 broadcast
            a0 = fmaf(xv.x, wreg[k4 * 4 + 0], a0);
            a1 = fmaf(xv.y, wreg[k4 * 4 + 1], a1);
            a2 = fmaf(xv.z, wreg[k4 * 4 + 2], a2);
            a3 = fmaf(xv.w, wreg[k4 * 4 + 3], a3);
        }
        int row = base + m0 + m;
        if (row < N_NODES)
            h[(size_t)row * DIM + lane] = (a0 + a1) + (a2 + a3);
    }
}

__global__ void __launch_bounds__(256, 4) k_gemm(const float* __restrict__ x,
                                                 const float* __restrict__ W,
                                                 float* __restrict__ h) {
    gemm_block(blockIdx.x, x, W, h);
}

// ---------------- fused: gemm1 (blocks 0..1562)  ||  ELL fill (rest) --------

__global__ void __launch_bounds__(256, 4) k_pre(const int* __restrict__ ei,
                                                const float* __restrict__ x,
                                                const float* __restrict__ W1,
                                                int* __restrict__ cur,
                                                int* __restrict__ ell_i,
                                                float* __restrict__ h) {
    if (blockIdx.x < GEMM_BLOCKS) {
        gemm_block(blockIdx.x, x, W1, h);
        return;
    }
    int e = (blockIdx.x - GEMM_BLOCKS) * 256 + threadIdx.x;
    if (e < N_EDGES) {
        int s = ei[e], d = ei[N_EDGES + e];
        int pos = atomicAdd(&cur[d], 1);
        ell_i[(size_t)(d * ELL_SLOTS + 1 + pos) * 2] = s;   // .s field only
    }
}

// ---------------- nrm pass: self-loop, edge norms, zero-fill ALL unused -----
// Thread per slot; block = 320 threads = exactly 8 nodes. Zeroing every unused
// slot (not just pad-to-8) makes the gather's fixed 24-slot unroll safe.

__global__ void k_nrm(const int* __restrict__ cur, Edge* __restrict__ ell) {
    int tid = threadIdx.x;
    int node = blockIdx.x * 8 + tid / ELL_SLOTS;
    int i = tid % ELL_SLOTS;
    int deg = cur[node];
    float dd = rsqrtf((float)(deg + 1));
    int ct1 = deg + 1;
    Edge* p = ell + (size_t)node * ELL_SLOTS + i;
    if (i == 0) {
        Edge e; e.s = node; e.nrm = dd * dd; *p = e;         // self-loop
    } else if (i < ct1) {
        int s = p->s;                                        // written by fill
        p->nrm = rsqrtf((float)(cur[s] + 1)) * dd;
    } else {
        Edge e; e.s = 0; e.nrm = 0.f; *p = e;                // zero (safe to read)
    }
}

// ---------------- gather: out = relu?( A_hat @ h + b ) ----------------------
// One wave per node, lane = column. Straight-line first 24 slots (12 int4 ELL
// loads + 24 independent coalesced row gathers, all in flight); rare uniform
// branch for deg+1 > 24 (P ~ 0.1%). Pad slots load row 0 (L1-hot) * nrm 0.

template <bool RELU_OUT>
__global__ void k_gather(const float* __restrict__ h, const int* __restrict__ cur,
                         const int4* __restrict__ ell4, const float* __restrict__ b,
                         float* __restrict__ out) {
    int node = blockIdx.x * 4 + (threadIdx.x >> 6);     // 25000*4 = 100000 exact
    const int lane = threadIdx.x & 63;
    const int4* p = ell4 + (size_t)node * (ELL_SLOTS / 2);
    int ct1 = __builtin_amdgcn_readfirstlane(cur[node]) + 1;

    int4 e[12];
#pragma unroll
    for (int i = 0; i < 12; ++i) e[i] = p[i];
    float v[24];
#pragma unroll
    for (int i = 0; i < 12; ++i) {
        v[2 * i]     = h[(size_t)e[i].x * DIM + lane];
        v[2 * i + 1] = h[(size_t)e[i].z * DIM + lane];
    }
    float acc = b[lane];
#pragma unroll
    for (int i = 0; i < 12; ++i) {
        acc = fmaf(v[2 * i],     __int_as_float(e[i].y), acc);
        acc = fmaf(v[2 * i + 1], __int_as_float(e[i].w), acc);
    }
    if (ct1 > 24) {                                      // rare, wave-uniform
#pragma unroll
        for (int i = 12; i < 20; ++i) {
            int4 ee = p[i];
            float va = h[(size_t)ee.x * DIM + lane];
            float vb = h[(size_t)ee.z * DIM + lane];
            acc = fmaf(va, __int_as_float(ee.y), acc);
            acc = fmaf(vb, __int_as_float(ee.w), acc);
        }
    }
    if (RELU_OUT) acc = fmaxf(acc, 0.f);
    out[(size_t)node * DIM + lane] = acc;
}

// ---------------- launch ----------------

extern "C" void kernel_launch(void* const* d_in, const int* in_sizes, int n_in,
                              void* d_out, int out_size, void* d_ws, size_t ws_size,
                              hipStream_t stream) {
    const float* x   = (const float*)d_in[0];
    const int*   ei  = (const int*)d_in[1];     // [2, E] row-major
    const float* W1  = (const float*)d_in[2];
    const float* b1  = (const float*)d_in[3];
    const float* W2  = (const float*)d_in[4];
    const float* b2  = (const float*)d_in[5];
    const float* W3  = (const float*)d_in[6];
    const float* b3  = (const float*)d_in[7];
    float* out = (float*)d_out;

    // ws layout (256B-aligned)
    char* ws = (char*)d_ws;
    int*   cur  = (int*)ws;                              // 400 KB (degree counts)
    Edge*  ell  = (Edge*)(ws + 0x80000);                 // 32.0 MB
    float* bufA = (float*)(ws + 0x80000 + 0x1E88000);    // 25.6 MB
    float* bufB = (float*)(ws + 0x80000 + 0x1E88000 + 0x1A00000);  // 25.6 MB

    hipMemsetAsync(cur, 0, N_NODES * sizeof(int), stream);

    // fused: gemm1 (x @ W1 -> bufA)  ||  ELL fill
    k_pre<<<GEMM_BLOCKS + FILL_BLOCKS, 256, 0, stream>>>(ei, x, W1, cur, (int*)ell, bufA);
    k_nrm<<<N_NODES / 8, 320, 0, stream>>>(cur, ell);

    const int gather_blocks = N_NODES / 4;   // 25000 (1 wave/node)

    // Layer 1 aggregation
    k_gather<true><<<gather_blocks, 256, 0, stream>>>(bufA, cur, (const int4*)ell, b1, bufB);
    // Layer 2
    k_gemm<<<GEMM_BLOCKS, 256, 0, stream>>>(bufB, W2, bufA);
    k_gather<true><<<gather_blocks, 256, 0, stream>>>(bufA, cur, (const int4*)ell, b2, bufB);
    // Layer 3
    k_gemm<<<GEMM_BLOCKS, 256, 0, stream>>>(bufB, W3, bufA);
    k_gather<false><<<gather_blocks, 256, 0, stream>>>(bufA, cur, (const int4*)ell, b3, out);
}

// Round 9
// 391.752 us; speedup vs baseline: 1.1054x; 1.1054x over previous
//
#include <hip/hip_runtime.h>
#include <math.h>

#define N_NODES 100000
#define N_EDGES 1200000
#define DIM 64
#define ELL_SLOTS 40      // max (deg+1); Poisson(12) => P(deg>=40) ~ 1e-10
#define GEMM_BLOCKS ((N_NODES + 63) / 64)    // 1563 (64 nodes/block)
#define FILL_BLOCKS ((N_EDGES + 255) / 256)  // 4688

struct Edge { int s; float nrm; };   // 8B

// bf16 pack/unpack (RTNE); h values are finite
__device__ __forceinline__ unsigned short f2bf(float f) {
    union { float f; unsigned int u; } v; v.f = f;
    unsigned int r = v.u + 0x7FFF + ((v.u >> 16) & 1);
    return (unsigned short)(r >> 16);
}
__device__ __forceinline__ float bf2f(unsigned short us) {
    return __uint_as_float((unsigned int)us << 16);
}

// ---------------- gemm tile: 64 nodes/block, LDS-staged x, W in VGPRs -------
// Output h in bf16 (halves the gather's random-line traffic).

__device__ __forceinline__ void gemm_block(int bid, const float* __restrict__ x,
                                           const float* __restrict__ W,
                                           unsigned short* __restrict__ h) {
    __shared__ float4 Xlds[1024];           // 64 rows x 16 float4 = 16 KB
    const int tid = threadIdx.x;
    const int lane = tid & 63;

    float wreg[64];                         // W column for this lane (L2-hot)
#pragma unroll
    for (int k = 0; k < 64; ++k) wreg[k] = W[k * DIM + lane];

    const int base = bid * 64;
#pragma unroll
    for (int it = 0; it < 4; ++it) {
        int f = tid + it * 256;             // float4 index in tile
        int row = base + (f >> 4);
        if (row >= N_NODES) row = N_NODES - 1;          // clamp (value unused)
        Xlds[f] = ((const float4*)x)[row * 16 + (f & 15)];
    }
    __syncthreads();

    const int m0 = (tid >> 6) * 16;         // wave's 16 rows
    for (int m = 0; m < 16; ++m) {
        const float4* xr = &Xlds[(m0 + m) * 16];
        float a0 = 0.f, a1 = 0.f, a2 = 0.f, a3 = 0.f;
#pragma unroll
        for (int k4 = 0; k4 < 16; ++k4) {
            float4 xv = xr[k4];             // uniform b128 broadcast
            a0 = fmaf(xv.x, wreg[k4 * 4 + 0], a0);
            a1 = fmaf(xv.y, wreg[k4 * 4 + 1], a1);
            a2 = fmaf(xv.z, wreg[k4 * 4 + 2], a2);
            a3 = fmaf(xv.w, wreg[k4 * 4 + 3], a3);
        }
        int row = base + m0 + m;
        if (row < N_NODES)
            h[(size_t)row * DIM + lane] = f2bf((a0 + a1) + (a2 + a3));
    }
}

__global__ void __launch_bounds__(256, 4) k_gemm(const float* __restrict__ x,
                                                 const float* __restrict__ W,
                                                 unsigned short* __restrict__ h) {
    gemm_block(blockIdx.x, x, W, h);
}

// ---------------- fused: gemm1 (blocks 0..1562)  ||  ELL fill (rest) --------

__global__ void __launch_bounds__(256, 4) k_pre(const int* __restrict__ ei,
                                                const float* __restrict__ x,
                                                const float* __restrict__ W1,
                                                int* __restrict__ cur,
                                                int* __restrict__ ell_i,
                                                unsigned short* __restrict__ h) {
    if (blockIdx.x < GEMM_BLOCKS) {
        gemm_block(blockIdx.x, x, W1, h);
        return;
    }
    int e = (blockIdx.x - GEMM_BLOCKS) * 256 + threadIdx.x;
    if (e < N_EDGES) {
        int s = ei[e], d = ei[N_EDGES + e];
        int pos = atomicAdd(&cur[d], 1);
        ell_i[(size_t)(d * ELL_SLOTS + 1 + pos) * 2] = s;   // .s field only
    }
}

// ---------------- nrm pass: self-loop, edge norms, zero-pad to mult of 8 ----

__global__ void k_nrm(const int* __restrict__ cur, Edge* __restrict__ ell) {
    int tid = threadIdx.x;
    int node = blockIdx.x * 8 + tid / ELL_SLOTS;
    int i = tid % ELL_SLOTS;
    int deg = cur[node];
    float dd = rsqrtf((float)(deg + 1));
    int ct1 = deg + 1;
    int pad = (ct1 + 7) & ~7;
    Edge* p = ell + (size_t)node * ELL_SLOTS + i;
    if (i == 0) {
        Edge e; e.s = node; e.nrm = dd * dd; *p = e;         // self-loop
    } else if (i < ct1) {
        int s = p->s;                                        // written by fill
        p->nrm = rsqrtf((float)(cur[s] + 1)) * dd;
    } else if (i < pad) {
        Edge e; e.s = 0; e.nrm = 0.f; *p = e;                // zero pad
    }                                                        // slots >= pad: never read
}

// ---------------- gather: out = relu?( A_hat @ h + b ) ----------------------
// One wave per node, lane = column. bf16 h rows (128B = 2 lines). Full batches
// of 8 slots: 4 uniform int4 ELL loads + 8 independent row gathers in flight.

template <bool RELU_OUT>
__global__ void k_gather(const unsigned short* __restrict__ h,
                         const int* __restrict__ cur,
                         const int4* __restrict__ ell4, const float* __restrict__ b,
                         float* __restrict__ out) {
    int node = blockIdx.x * 4 + (threadIdx.x >> 6);     // 25000*4 = 100000 exact
    const int lane = threadIdx.x & 63;

    int nb = __builtin_amdgcn_readfirstlane((cur[node] + 8) >> 3);  // ceil((deg+1)/8)
    const int4* p = ell4 + (size_t)node * (ELL_SLOTS / 2);

    float acc = b[lane];
    for (int bi = 0; bi < nb; ++bi, p += 4) {
        int4 e0 = p[0];
        int4 e1 = p[1];
        int4 e2 = p[2];
        int4 e3 = p[3];
        float v0 = bf2f(h[(size_t)e0.x * DIM + lane]);
        float v1 = bf2f(h[(size_t)e0.z * DIM + lane]);
        float v2 = bf2f(h[(size_t)e1.x * DIM + lane]);
        float v3 = bf2f(h[(size_t)e1.z * DIM + lane]);
        float v4 = bf2f(h[(size_t)e2.x * DIM + lane]);
        float v5 = bf2f(h[(size_t)e2.z * DIM + lane]);
        float v6 = bf2f(h[(size_t)e3.x * DIM + lane]);
        float v7 = bf2f(h[(size_t)e3.z * DIM + lane]);
        acc = fmaf(v0, __int_as_float(e0.y), acc);
        acc = fmaf(v1, __int_as_float(e0.w), acc);
        acc = fmaf(v2, __int_as_float(e1.y), acc);
        acc = fmaf(v3, __int_as_float(e1.w), acc);
        acc = fmaf(v4, __int_as_float(e2.y), acc);
        acc = fmaf(v5, __int_as_float(e2.w), acc);
        acc = fmaf(v6, __int_as_float(e3.y), acc);
        acc = fmaf(v7, __int_as_float(e3.w), acc);
    }
    if (RELU_OUT) acc = fmaxf(acc, 0.f);
    out[(size_t)node * DIM + lane] = acc;
}

// ---------------- launch ----------------

extern "C" void kernel_launch(void* const* d_in, const int* in_sizes, int n_in,
                              void* d_out, int out_size, void* d_ws, size_t ws_size,
                              hipStream_t stream) {
    const float* x   = (const float*)d_in[0];
    const int*   ei  = (const int*)d_in[1];     // [2, E] row-major
    const float* W1  = (const float*)d_in[2];
    const float* b1  = (const float*)d_in[3];
    const float* W2  = (const float*)d_in[4];
    const float* b2  = (const float*)d_in[5];
    const float* W3  = (const float*)d_in[6];
    const float* b3  = (const float*)d_in[7];
    float* out = (float*)d_out;

    // ws layout (256B-aligned)
    char* ws = (char*)d_ws;
    int*            cur  = (int*)ws;                               // 400 KB
    Edge*           ell  = (Edge*)(ws + 0x80000);                  // 32.0 MB
    unsigned short* hbuf = (unsigned short*)(ws + 0x80000 + 0x1E88000);  // 12.8 MB (bf16)
    float*          gbuf = (float*)(ws + 0x80000 + 0x1E88000 + 0xD00000); // 25.6 MB (fp32)

    hipMemsetAsync(cur, 0, N_NODES * sizeof(int), stream);

    // fused: gemm1 (x @ W1 -> hbuf bf16)  ||  ELL fill
    k_pre<<<GEMM_BLOCKS + FILL_BLOCKS, 256, 0, stream>>>(ei, x, W1, cur, (int*)ell, hbuf);
    k_nrm<<<N_NODES / 8, 320, 0, stream>>>(cur, ell);

    const int gather_blocks = N_NODES / 4;   // 25000 (1 wave/node)

    // Layer 1 aggregation (fp32 out)
    k_gather<true><<<gather_blocks, 256, 0, stream>>>(hbuf, cur, (const int4*)ell, b1, gbuf);
    // Layer 2
    k_gemm<<<GEMM_BLOCKS, 256, 0, stream>>>(gbuf, W2, hbuf);
    k_gather<true><<<gather_blocks, 256, 0, stream>>>(hbuf, cur, (const int4*)ell, b2, gbuf);
    // Layer 3
    k_gemm<<<GEMM_BLOCKS, 256, 0, stream>>>(gbuf, W3, hbuf);
    k_gather<false><<<gather_blocks, 256, 0, stream>>>(hbuf, cur, (const int4*)ell, b3, out);
}

// Round 10
// 366.410 us; speedup vs baseline: 1.1818x; 1.0692x over previous
//
#include <hip/hip_runtime.h>
#include <math.h>

#define N_NODES 100000
#define N_EDGES 1200000
#define DIM 64
#define ELL_STRIDE 48     // ints per node row (192 B = 3 lines); deg<=48 safe
#define GEMM_BLOCKS ((N_NODES + 63) / 64)    // 1563 (64 nodes/block)
#define FILL_BLOCKS ((N_EDGES + 255) / 256)  // 4688

// bf16 pack/unpack (RTNE)
__device__ __forceinline__ unsigned short f2bf(float f) {
    union { float f; unsigned int u; } v; v.f = f;
    unsigned int r = v.u + 0x7FFF + ((v.u >> 16) & 1);
    return (unsigned short)(r >> 16);
}
__device__ __forceinline__ float bf2f(unsigned short us) {
    return __uint_as_float((unsigned int)us << 16);
}

// ---------------- gemm tile: 64 nodes/block, LDS-staged x, W in VGPRs -------
// SCALE: multiply output row by dinv[row] (rows pre-scaled for the gather).

template <bool SCALE>
__device__ __forceinline__ void gemm_block(int bid, const float* __restrict__ x,
                                           const float* __restrict__ W,
                                           unsigned short* __restrict__ h,
                                           const int* __restrict__ cur) {
    __shared__ float4 Xlds[1024];           // 64 rows x 16 float4 = 16 KB
    const int tid = threadIdx.x;
    const int lane = tid & 63;

    float wreg[64];                         // W column for this lane (L2-hot)
#pragma unroll
    for (int k = 0; k < 64; ++k) wreg[k] = W[k * DIM + lane];

    const int base = bid * 64;
#pragma unroll
    for (int it = 0; it < 4; ++it) {
        int f = tid + it * 256;             // float4 index in tile
        int row = base + (f >> 4);
        if (row >= N_NODES) row = N_NODES - 1;          // clamp (value unused)
        Xlds[f] = ((const float4*)x)[row * 16 + (f & 15)];
    }
    __syncthreads();

    const int m0 = (tid >> 6) * 16;         // wave's 16 rows
    for (int m = 0; m < 16; ++m) {
        const float4* xr = &Xlds[(m0 + m) * 16];
        float a0 = 0.f, a1 = 0.f, a2 = 0.f, a3 = 0.f;
#pragma unroll
        for (int k4 = 0; k4 < 16; ++k4) {
            float4 xv = xr[k4];             // uniform b128 broadcast
            a0 = fmaf(xv.x, wreg[k4 * 4 + 0], a0);
            a1 = fmaf(xv.y, wreg[k4 * 4 + 1], a1);
            a2 = fmaf(xv.z, wreg[k4 * 4 + 2], a2);
            a3 = fmaf(xv.w, wreg[k4 * 4 + 3], a3);
        }
        int row = base + m0 + m;
        if (row < N_NODES) {
            float res = (a0 + a1) + (a2 + a3);
            if (SCALE) res *= rsqrtf((float)(cur[row] + 1));
            h[(size_t)row * DIM + lane] = f2bf(res);
        }
    }
}

__global__ void __launch_bounds__(256, 4) k_gemm(const float* __restrict__ x,
                                                 const float* __restrict__ W,
                                                 unsigned short* __restrict__ h,
                                                 const int* __restrict__ cur) {
    gemm_block<true>(blockIdx.x, x, W, h, cur);
}

// ---------------- fused: gemm1 (blocks 0..1562)  ||  ELL fill (rest) --------
// ELL stores ONLY the src index (4 B/edge). gemm1 output is UNscaled (cur
// isn't final yet); k_scale fixes it up after.

__global__ void __launch_bounds__(256, 4) k_pre(const int* __restrict__ ei,
                                                const float* __restrict__ x,
                                                const float* __restrict__ W1,
                                                int* __restrict__ cur,
                                                int* __restrict__ ell,
                                                unsigned short* __restrict__ h) {
    if (blockIdx.x < GEMM_BLOCKS) {
        gemm_block<false>(blockIdx.x, x, W1, h, nullptr);
        return;
    }
    int e = (blockIdx.x - GEMM_BLOCKS) * 256 + threadIdx.x;
    if (e < N_EDGES) {
        int s = ei[e], d = ei[N_EDGES + e];
        int pos = atomicAdd(&cur[d], 1);
        ell[(size_t)d * ELL_STRIDE + pos] = s;
    }
}

// ---------------- pad pass: unused slots -> dummy row index ----------------
// Slots [deg, max(16, ceil8(deg))) point at row N_NODES (all-zero, L2-hot).
// Block = 384 threads = 8 nodes x 48 slots.

__global__ void k_nrm(const int* __restrict__ cur, int* __restrict__ ell) {
    int tid = threadIdx.x;
    int node = blockIdx.x * 8 + tid / ELL_STRIDE;
    int i = tid % ELL_STRIDE;
    int deg = cur[node];
    int pe = (deg + 7) & ~7;
    if (pe < 16) pe = 16;
    if (i >= deg && i < pe) ell[(size_t)node * ELL_STRIDE + i] = N_NODES;
}

// ---------------- scale pass: h1 *= dinv[row]; zero dummy row --------------
// Thread per uint4 (8 bf16). Rows 0..N_NODES inclusive (dummy row -> 0).

__device__ __forceinline__ unsigned int scale2(unsigned int u, float dd) {
    float lo = __uint_as_float(u << 16) * dd;
    float hi = __uint_as_float(u & 0xFFFF0000u) * dd;
    return (unsigned int)f2bf(lo) | ((unsigned int)f2bf(hi) << 16);
}

__global__ void k_scale(unsigned short* __restrict__ h, const int* __restrict__ cur) {
    int gid = blockIdx.x * 256 + threadIdx.x;        // uint4 index
    if (gid >= (N_NODES + 1) * 8) return;
    int row = gid >> 3;
    uint4* p = (uint4*)h + gid;
    if (row == N_NODES) { *p = make_uint4(0, 0, 0, 0); return; }
    float dd = rsqrtf((float)(cur[row] + 1));
    uint4 v = *p;
    v.x = scale2(v.x, dd);
    v.y = scale2(v.y, dd);
    v.z = scale2(v.z, dd);
    v.w = scale2(v.w, dd);
    *p = v;
}

// ---------------- gather: out = relu?( dinv[d]*(sum h'[s] + h'[d]) + b ) ----
// One wave per node, lane = column. Pure adds (rows pre-scaled). Straight-line
// first 16 slots (84% of nodes fully covered; pads hit the zero dummy row,
// L2-hot); rare wave-uniform tail loop for deg > 16.

template <bool RELU_OUT>
__global__ void k_gather(const unsigned short* __restrict__ h,
                         const int* __restrict__ cur,
                         const int* __restrict__ ell, const float* __restrict__ b,
                         float* __restrict__ out) {
    int node = blockIdx.x * 4 + (threadIdx.x >> 6);     // 25000*4 = 100000 exact
    const int lane = threadIdx.x & 63;
    int deg = __builtin_amdgcn_readfirstlane(cur[node]);
    const int* row = ell + (size_t)node * ELL_STRIDE;

    int4 e0 = ((const int4*)row)[0];
    int4 e1 = ((const int4*)row)[1];
    int4 e2 = ((const int4*)row)[2];
    int4 e3 = ((const int4*)row)[3];
    float own = bf2f(h[(size_t)node * DIM + lane]);     // self-loop (coalesced)

    float v0  = bf2f(h[(size_t)e0.x * DIM + lane]);
    float v1  = bf2f(h[(size_t)e0.y * DIM + lane]);
    float v2  = bf2f(h[(size_t)e0.z * DIM + lane]);
    float v3  = bf2f(h[(size_t)e0.w * DIM + lane]);
    float v4  = bf2f(h[(size_t)e1.x * DIM + lane]);
    float v5  = bf2f(h[(size_t)e1.y * DIM + lane]);
    float v6  = bf2f(h[(size_t)e1.z * DIM + lane]);
    float v7  = bf2f(h[(size_t)e1.w * DIM + lane]);
    float v8  = bf2f(h[(size_t)e2.x * DIM + lane]);
    float v9  = bf2f(h[(size_t)e2.y * DIM + lane]);
    float v10 = bf2f(h[(size_t)e2.z * DIM + lane]);
    float v11 = bf2f(h[(size_t)e2.w * DIM + lane]);
    float v12 = bf2f(h[(size_t)e3.x * DIM + lane]);
    float v13 = bf2f(h[(size_t)e3.y * DIM + lane]);
    float v14 = bf2f(h[(size_t)e3.z * DIM + lane]);
    float v15 = bf2f(h[(size_t)e3.w * DIM + lane]);

    float acc = ((own + v0) + (v1 + v2)) + ((v3 + v4) + (v5 + v6))
              + ((v7 + v8) + (v9 + v10)) + ((v11 + v12) + ((v13 + v14) + v15));

    if (deg > 16) {                                     // rare, wave-uniform
        int pe = (deg + 7) & ~7;
        for (int k = 16; k < pe; k += 8) {
            int4 a = *(const int4*)(row + k);
            int4 c = *(const int4*)(row + k + 4);
            float w0 = bf2f(h[(size_t)a.x * DIM + lane]);
            float w1 = bf2f(h[(size_t)a.y * DIM + lane]);
            float w2 = bf2f(h[(size_t)a.z * DIM + lane]);
            float w3 = bf2f(h[(size_t)a.w * DIM + lane]);
            float w4 = bf2f(h[(size_t)c.x * DIM + lane]);
            float w5 = bf2f(h[(size_t)c.y * DIM + lane]);
            float w6 = bf2f(h[(size_t)c.z * DIM + lane]);
            float w7 = bf2f(h[(size_t)c.w * DIM + lane]);
            acc += ((w0 + w1) + (w2 + w3)) + ((w4 + w5) + (w6 + w7));
        }
    }

    float dd = rsqrtf((float)(deg + 1));
    float o = fmaf(acc, dd, b[lane]);
    if (RELU_OUT) o = fmaxf(o, 0.f);
    out[(size_t)node * DIM + lane] = o;
}

// ---------------- launch ----------------

extern "C" void kernel_launch(void* const* d_in, const int* in_sizes, int n_in,
                              void* d_out, int out_size, void* d_ws, size_t ws_size,
                              hipStream_t stream) {
    const float* x   = (const float*)d_in[0];
    const int*   ei  = (const int*)d_in[1];     // [2, E] row-major
    const float* W1  = (const float*)d_in[2];
    const float* b1  = (const float*)d_in[3];
    const float* W2  = (const float*)d_in[4];
    const float* b2  = (const float*)d_in[5];
    const float* W3  = (const float*)d_in[6];
    const float* b3  = (const float*)d_in[7];
    float* out = (float*)d_out;

    // ws layout (256B-aligned)
    char* ws = (char*)d_ws;
    int*            cur  = (int*)ws;                          // 400 KB
    int*            ell  = (int*)(ws + 0x80000);              // 19.2 MB
    unsigned short* hbuf = (unsigned short*)(ws + 0x1400000); // 12.8 MB (bf16, +dummy row)
    float*          gbuf = (float*)(ws + 0x2100000);          // 25.6 MB (fp32)

    hipMemsetAsync(cur, 0, N_NODES * sizeof(int), stream);

    // gemm1 (x @ W1 -> hbuf, unscaled)  ||  ELL fill (src index only)
    k_pre<<<GEMM_BLOCKS + FILL_BLOCKS, 256, 0, stream>>>(ei, x, W1, cur, ell, hbuf);
    k_nrm<<<N_NODES / 8, 384, 0, stream>>>(cur, ell);                 // pad slots
    k_scale<<<((N_NODES + 1) * 8 + 255) / 256, 256, 0, stream>>>(hbuf, cur);  // h*=dinv; dummy=0

    const int gather_blocks = N_NODES / 4;   // 25000 (1 wave/node)

    // Layer 1 aggregation (fp32 out)
    k_gather<true><<<gather_blocks, 256, 0, stream>>>(hbuf, cur, ell, b1, gbuf);
    // Layer 2 (gemm scales output rows by dinv)
    k_gemm<<<GEMM_BLOCKS, 256, 0, stream>>>(gbuf, W2, hbuf, cur);
    k_gather<true><<<gather_blocks, 256, 0, stream>>>(hbuf, cur, ell, b2, gbuf);
    // Layer 3
    k_gemm<<<GEMM_BLOCKS, 256, 0, stream>>>(gbuf, W3, hbuf, cur);
    k_gather<false><<<gather_blocks, 256, 0, stream>>>(hbuf, cur, ell, b3, out);
}

// Round 11
// 321.396 us; speedup vs baseline: 1.3473x; 1.1401x over previous
//
#include <hip/hip_runtime.h>
#include <math.h>

#define N_NODES 100000
#define N_EDGES 1200000
#define DIM 64
#define ELL_STRIDE 48        // ints per node row; deg<=48 safe (Poisson(12))
#define BNODES 128           // nodes per bucket (dst>>7)
#define NB ((N_NODES + BNODES - 1) / BNODES)   // 782 buckets
#define BUCKET_CAP 2048      // edges per bucket; mean 1536, +13 sigma
#define GEMM_BLOCKS ((N_NODES + 63) / 64)      // 1563 (64 nodes/block)
#define FILL_BLOCKS ((N_EDGES + 255) / 256)    // 4688

// bf16 pack/unpack (RTNE)
__device__ __forceinline__ unsigned short f2bf(float f) {
    union { float f; unsigned int u; } v; v.f = f;
    unsigned int r = v.u + 0x7FFF + ((v.u >> 16) & 1);
    return (unsigned short)(r >> 16);
}
__device__ __forceinline__ float bf2f(unsigned short us) {
    return __uint_as_float((unsigned int)us << 16);
}

// ---------------- init: bucket tails (strided 16 ints = 1 line apart) -------

__global__ void k_init(int* __restrict__ tail) {
    int b = blockIdx.x * 256 + threadIdx.x;
    if (b < NB) tail[b * 16] = b * BUCKET_CAP;
}

// ---------------- gemm tile: 64 nodes/block, LDS-staged x, W in VGPRs -------

template <bool SCALE>
__device__ __forceinline__ void gemm_block(int bid, const float* __restrict__ x,
                                           const float* __restrict__ W,
                                           unsigned short* __restrict__ h,
                                           const int* __restrict__ deg) {
    __shared__ float4 Xlds[1024];           // 64 rows x 16 float4 = 16 KB
    const int tid = threadIdx.x;
    const int lane = tid & 63;

    float wreg[64];                         // W column for this lane (L2-hot)
#pragma unroll
    for (int k = 0; k < 64; ++k) wreg[k] = W[k * DIM + lane];

    const int base = bid * 64;
#pragma unroll
    for (int it = 0; it < 4; ++it) {
        int f = tid + it * 256;             // float4 index in tile
        int row = base + (f >> 4);
        if (row >= N_NODES) row = N_NODES - 1;          // clamp (value unused)
        Xlds[f] = ((const float4*)x)[row * 16 + (f & 15)];
    }
    __syncthreads();

    const int m0 = (tid >> 6) * 16;         // wave's 16 rows
    for (int m = 0; m < 16; ++m) {
        const float4* xr = &Xlds[(m0 + m) * 16];
        float a0 = 0.f, a1 = 0.f, a2 = 0.f, a3 = 0.f;
#pragma unroll
        for (int k4 = 0; k4 < 16; ++k4) {
            float4 xv = xr[k4];             // uniform b128 broadcast
            a0 = fmaf(xv.x, wreg[k4 * 4 + 0], a0);
            a1 = fmaf(xv.y, wreg[k4 * 4 + 1], a1);
            a2 = fmaf(xv.z, wreg[k4 * 4 + 2], a2);
            a3 = fmaf(xv.w, wreg[k4 * 4 + 3], a3);
        }
        int row = base + m0 + m;
        if (row < N_NODES) {
            float res = (a0 + a1) + (a2 + a3);
            if (SCALE) res *= rsqrtf((float)(deg[row] + 1));
            h[(size_t)row * DIM + lane] = f2bf(res);
        }
    }
}

__global__ void __launch_bounds__(256, 4) k_gemm(const float* __restrict__ x,
                                                 const float* __restrict__ W,
                                                 unsigned short* __restrict__ h,
                                                 const int* __restrict__ deg) {
    gemm_block<true>(blockIdx.x, x, W, h, deg);
}

// ---------------- fused: gemm1 (blocks 0..1562)  ||  bucket partition -------
// Partition appends {src,dst} to bucket dst>>7; tail lines stay L2-hot so
// the 8B stores land sequentially per bucket (no random-line write storm).

__global__ void __launch_bounds__(256, 4) k_pre(const int* __restrict__ ei,
                                                const float* __restrict__ x,
                                                const float* __restrict__ W1,
                                                int* __restrict__ tail,
                                                int2* __restrict__ part,
                                                unsigned short* __restrict__ h) {
    if (blockIdx.x < GEMM_BLOCKS) {
        gemm_block<false>(blockIdx.x, x, W1, h, nullptr);
        return;
    }
    int e = (blockIdx.x - GEMM_BLOCKS) * 256 + threadIdx.x;
    if (e < N_EDGES) {
        int s = ei[e], d = ei[N_EDGES + e];
        int pos = atomicAdd(&tail[(d >> 7) * 16], 1);
        part[pos] = make_int2(s, d);
    }
}

// ---------------- build: per-bucket ELL slab in LDS, streamed out -----------
// One block per bucket (128 nodes). LDS-atomic counts + LDS scatter; pad to
// max(16, ceil8(deg)) with dummy row; coalesced int4 stream to global.

__global__ void __launch_bounds__(256) k_build(const int2* __restrict__ part,
                                               const int* __restrict__ tail,
                                               int* __restrict__ ell,
                                               int* __restrict__ deg) {
    __shared__ int lcur[BNODES];
    __shared__ int lell[BNODES * ELL_STRIDE];   // 24 KB
    const int bucket = blockIdx.x;
    const int tid = threadIdx.x;

    for (int i = tid; i < BNODES; i += 256) lcur[i] = 0;
    __syncthreads();

    int n = tail[bucket * 16] - bucket * BUCKET_CAP;
    const int2* pb = part + (size_t)bucket * BUCKET_CAP;
    for (int i = tid; i < n; i += 256) {
        int2 e = pb[i];
        int ld = e.y - bucket * BNODES;
        int pos = atomicAdd(&lcur[ld], 1);
        lell[ld * ELL_STRIDE + pos] = e.x;
    }
    __syncthreads();

    for (int idx = tid; idx < BNODES * ELL_STRIDE; idx += 256) {
        int ln = idx / ELL_STRIDE, sl = idx - ln * ELL_STRIDE;
        int dg = lcur[ln];
        int pe = (dg + 7) & ~7;
        if (pe < 16) pe = 16;
        if (sl >= dg && sl < pe) lell[idx] = N_NODES;   // dummy zero row
    }
    __syncthreads();

    int4* dst4 = (int4*)(ell + (size_t)bucket * BNODES * ELL_STRIDE);
    const int4* src4 = (const int4*)lell;
    for (int i = tid; i < BNODES * ELL_STRIDE / 4; i += 256) dst4[i] = src4[i];
    for (int i = tid; i < BNODES; i += 256) deg[bucket * BNODES + i] = lcur[i];
}

// ---------------- scale pass: h1 *= dinv[row]; zero dummy row --------------

__device__ __forceinline__ unsigned int scale2(unsigned int u, float dd) {
    float lo = __uint_as_float(u << 16) * dd;
    float hi = __uint_as_float(u & 0xFFFF0000u) * dd;
    return (unsigned int)f2bf(lo) | ((unsigned int)f2bf(hi) << 16);
}

__global__ void k_scale(unsigned short* __restrict__ h, const int* __restrict__ deg) {
    int gid = blockIdx.x * 256 + threadIdx.x;        // uint4 index (8 bf16)
    if (gid >= (N_NODES + 1) * 8) return;
    int row = gid >> 3;
    uint4* p = (uint4*)h + gid;
    if (row == N_NODES) { *p = make_uint4(0, 0, 0, 0); return; }
    float dd = rsqrtf((float)(deg[row] + 1));
    uint4 v = *p;
    v.x = scale2(v.x, dd);
    v.y = scale2(v.y, dd);
    v.z = scale2(v.z, dd);
    v.w = scale2(v.w, dd);
    *p = v;
}

// ---------------- gather: out = relu?( dinv[d]*(sum h'[s] + h'[d]) + b ) ----

template <bool RELU_OUT>
__global__ void k_gather(const unsigned short* __restrict__ h,
                         const int* __restrict__ deg,
                         const int* __restrict__ ell, const float* __restrict__ b,
                         float* __restrict__ out) {
    int node = blockIdx.x * 4 + (threadIdx.x >> 6);     // 25000*4 = 100000 exact
    const int lane = threadIdx.x & 63;
    int dg = __builtin_amdgcn_readfirstlane(deg[node]);
    const int* row = ell + (size_t)node * ELL_STRIDE;

    int4 e0 = ((const int4*)row)[0];
    int4 e1 = ((const int4*)row)[1];
    int4 e2 = ((const int4*)row)[2];
    int4 e3 = ((const int4*)row)[3];
    float own = bf2f(h[(size_t)node * DIM + lane]);     // self-loop (coalesced)

    float v0  = bf2f(h[(size_t)e0.x * DIM + lane]);
    float v1  = bf2f(h[(size_t)e0.y * DIM + lane]);
    float v2  = bf2f(h[(size_t)e0.z * DIM + lane]);
    float v3  = bf2f(h[(size_t)e0.w * DIM + lane]);
    float v4  = bf2f(h[(size_t)e1.x * DIM + lane]);
    float v5  = bf2f(h[(size_t)e1.y * DIM + lane]);
    float v6  = bf2f(h[(size_t)e1.z * DIM + lane]);
    float v7  = bf2f(h[(size_t)e1.w * DIM + lane]);
    float v8  = bf2f(h[(size_t)e2.x * DIM + lane]);
    float v9  = bf2f(h[(size_t)e2.y * DIM + lane]);
    float v10 = bf2f(h[(size_t)e2.z * DIM + lane]);
    float v11 = bf2f(h[(size_t)e2.w * DIM + lane]);
    float v12 = bf2f(h[(size_t)e3.x * DIM + lane]);
    float v13 = bf2f(h[(size_t)e3.y * DIM + lane]);
    float v14 = bf2f(h[(size_t)e3.z * DIM + lane]);
    float v15 = bf2f(h[(size_t)e3.w * DIM + lane]);

    float acc = ((own + v0) + (v1 + v2)) + ((v3 + v4) + (v5 + v6))
              + ((v7 + v8) + (v9 + v10)) + ((v11 + v12) + ((v13 + v14) + v15));

    if (dg > 16) {                                      // rare, wave-uniform
        int pe = (dg + 7) & ~7;
        for (int k = 16; k < pe; k += 8) {
            int4 a = *(const int4*)(row + k);
            int4 c = *(const int4*)(row + k + 4);
            float w0 = bf2f(h[(size_t)a.x * DIM + lane]);
            float w1 = bf2f(h[(size_t)a.y * DIM + lane]);
            float w2 = bf2f(h[(size_t)a.z * DIM + lane]);
            float w3 = bf2f(h[(size_t)a.w * DIM + lane]);
            float w4 = bf2f(h[(size_t)c.x * DIM + lane]);
            float w5 = bf2f(h[(size_t)c.y * DIM + lane]);
            float w6 = bf2f(h[(size_t)c.z * DIM + lane]);
            float w7 = bf2f(h[(size_t)c.w * DIM + lane]);
            acc += ((w0 + w1) + (w2 + w3)) + ((w4 + w5) + (w6 + w7));
        }
    }

    float dd = rsqrtf((float)(dg + 1));
    float o = fmaf(acc, dd, b[lane]);
    if (RELU_OUT) o = fmaxf(o, 0.f);
    out[(size_t)node * DIM + lane] = o;
}

// ---------------- launch ----------------

extern "C" void kernel_launch(void* const* d_in, const int* in_sizes, int n_in,
                              void* d_out, int out_size, void* d_ws, size_t ws_size,
                              hipStream_t stream) {
    const float* x   = (const float*)d_in[0];
    const int*   ei  = (const int*)d_in[1];     // [2, E] row-major
    const float* W1  = (const float*)d_in[2];
    const float* b1  = (const float*)d_in[3];
    const float* W2  = (const float*)d_in[4];
    const float* b2  = (const float*)d_in[5];
    const float* W3  = (const float*)d_in[6];
    const float* b3  = (const float*)d_in[7];
    float* out = (float*)d_out;

    // ws layout (256B-aligned)
    char* ws = (char*)d_ws;
    int*            tailp = (int*)ws;                          // 50 KB (strided tails)
    int*            deg   = (int*)(ws + 0x10000);              // 400 KB (NB*BNODES)
    int2*           part  = (int2*)(ws + 0x80000);             // 12.8 MB (NB*2048*8)
    int*            ell   = (int*)(ws + 0xD00000);             // 19.2 MB (NB*BNODES*48*4)
    unsigned short* hbuf  = (unsigned short*)(ws + 0x2000000); // 12.8 MB (bf16 + dummy row)
    float*          gbuf  = (float*)(ws + 0x2D00000);          // 25.6 MB (fp32)

    k_init<<<(NB + 255) / 256, 256, 0, stream>>>(tailp);

    // gemm1 (x @ W1 -> hbuf, unscaled)  ||  bucket partition of edges
    k_pre<<<GEMM_BLOCKS + FILL_BLOCKS, 256, 0, stream>>>(ei, x, W1, tailp, part, hbuf);
    k_build<<<NB, 256, 0, stream>>>(part, tailp, ell, deg);
    k_scale<<<((N_NODES + 1) * 8 + 255) / 256, 256, 0, stream>>>(hbuf, deg);

    const int gather_blocks = N_NODES / 4;   // 25000 (1 wave/node)

    // Layer 1 aggregation (fp32 out)
    k_gather<true><<<gather_blocks, 256, 0, stream>>>(hbuf, deg, ell, b1, gbuf);
    // Layer 2 (gemm scales output rows by dinv)
    k_gemm<<<GEMM_BLOCKS, 256, 0, stream>>>(gbuf, W2, hbuf, deg);
    k_gather<true><<<gather_blocks, 256, 0, stream>>>(hbuf, deg, ell, b2, gbuf);
    // Layer 3
    k_gemm<<<GEMM_BLOCKS, 256, 0, stream>>>(gbuf, W3, hbuf, deg);
    k_gather<false><<<gather_blocks, 256, 0, stream>>>(hbuf, deg, ell, b3, out);
}